// Round 1
// baseline (242.470 us; speedup 1.0000x reference)
//
#include <hip/hip_runtime.h>
#include <hip/hip_bf16.h>

typedef __bf16 bf16x8 __attribute__((ext_vector_type(8)));
typedef float  f32x4  __attribute__((ext_vector_type(4)));

// Sizes (fixed by the problem)
//   q [1024][128] f32, k [1024][128] f32, queue [128][65536] f32,
//   prototypes [1000][128] f32, target [1024] int32
// Outputs (concat, f32):
//   logits [1024][65537], logits_proto [1024][1000],
//   new_queue [128][65536], new_prototypes [1000][128]

#define B_   1024
#define D_   128
#define K_   65536
#define C_   1000
#define LROW 65537
#define TINV 10.0f   // 1/TEMPERATURE

// ---------------- l_pos: logits[:,0] = (q·k)/T ----------------
__global__ __launch_bounds__(256) void lpos_kernel(const float* __restrict__ q,
                                                   const float* __restrict__ k,
                                                   float* __restrict__ logits) {
    const int wid  = threadIdx.x >> 6;
    const int lane = threadIdx.x & 63;
    const int row  = blockIdx.x * 4 + wid;
    const float2 qv = reinterpret_cast<const float2*>(q + (size_t)row * D_)[lane];
    const float2 kv = reinterpret_cast<const float2*>(k + (size_t)row * D_)[lane];
    float p = qv.x * kv.x + qv.y * kv.y;
    #pragma unroll
    for (int off = 32; off > 0; off >>= 1) p += __shfl_xor(p, off);
    if (lane == 0) logits[(size_t)row * LROW] = p * TINV;
}

// ---------------- big GEMM: logits[:,1:] = (q @ queue)/T ----------------
// grid (512, 8): x = col tile (128 cols), y = row tile (128 rows). 256 thr = 4 waves.
// Each wave owns a 32-col strip; A (q tile) staged bf16 in LDS, B read from global f32.
__global__ __launch_bounds__(256) void gemm_neg(const float* __restrict__ q,
                                                const float* __restrict__ queue,
                                                float* __restrict__ logits) {
    __shared__ __bf16 Alds[128][136];   // 272 B/row: 16B-aligned, bank-stride 4
    const int tid  = threadIdx.x;
    const int wid  = tid >> 6;
    const int lane = tid & 63;
    const int brow = blockIdx.y * 128;
    const int bcol = blockIdx.x * 128;

    // stage A: q[brow:brow+128][0:128] f32 -> bf16 LDS
    for (int it = 0; it < 16; ++it) {
        const int e = (it * 256 + tid) * 4;
        const int r = e >> 7, c = e & 127;
        const float4 v = *reinterpret_cast<const float4*>(q + (size_t)(brow + r) * D_ + c);
        union { __bf16 h[4]; unsigned long long u; } t;
        t.h[0] = (__bf16)v.x; t.h[1] = (__bf16)v.y; t.h[2] = (__bf16)v.z; t.h[3] = (__bf16)v.w;
        *reinterpret_cast<unsigned long long*>(&Alds[r][c]) = t.u;
    }
    __syncthreads();

    const int bl = lane & 15;     // col-in-tile / row-in-A-fragment
    const int gk = lane >> 4;     // k group
    const int colbase = bcol + wid * 32;

    f32x4 acc[8][2] = {};
    for (int s = 0; s < 4; ++s) {
        #pragma unroll
        for (int n = 0; n < 2; ++n) {
            // B fragment: queue[d = s*32+gk*8+v][j = colbase+n*16+bl], f32 -> bf16
            const float* bp = queue + (size_t)(s * 32 + gk * 8) * K_ + colbase + n * 16 + bl;
            bf16x8 bfrag;
            #pragma unroll
            for (int v = 0; v < 8; ++v) bfrag[v] = (__bf16)bp[(size_t)v * K_];
            #pragma unroll
            for (int m = 0; m < 8; ++m) {
                bf16x8 afrag = *reinterpret_cast<const bf16x8*>(&Alds[m * 16 + bl][s * 32 + gk * 8]);
                acc[m][n] = __builtin_amdgcn_mfma_f32_16x16x32_bf16(afrag, bfrag, acc[m][n], 0, 0, 0);
            }
        }
    }

    // C/D layout: col = lane&15, row = (lane>>4)*4 + r
    #pragma unroll
    for (int m = 0; m < 8; ++m)
        #pragma unroll
        for (int n = 0; n < 2; ++n)
            #pragma unroll
            for (int r = 0; r < 4; ++r) {
                const int orow = brow + m * 16 + (gk << 2) + r;
                const size_t off = (size_t)orow * LROW + 1 + colbase + n * 16 + bl;
                logits[off] = acc[m][n][r] * TINV;
            }
}

// ---------------- proto GEMM: logits_proto = (q @ protos^T)/T ----------------
// grid (63, 16), 256 thr = 4 waves; each wave one 16x16 tile, K=128.
__global__ __launch_bounds__(256) void gemm_proto(const float* __restrict__ q,
                                                  const float* __restrict__ protos,
                                                  float* __restrict__ out) {
    const int wid  = threadIdx.x >> 6;
    const int lane = threadIdx.x & 63;
    const int mrow = (blockIdx.y * 4 + wid) * 16;
    const int ncol = blockIdx.x * 16;
    const int bl = lane & 15, gk = lane >> 4;
    const int col = ncol + bl;
    const bool valid = (col < C_);

    f32x4 acc = {};
    for (int s = 0; s < 4; ++s) {
        const float* ap = q + (size_t)(mrow + bl) * D_ + s * 32 + gk * 8;
        bf16x8 a, b;
        #pragma unroll
        for (int v = 0; v < 8; ++v) a[v] = (__bf16)ap[v];
        if (valid) {
            const float* bp = protos + (size_t)col * D_ + s * 32 + gk * 8;
            #pragma unroll
            for (int v = 0; v < 8; ++v) b[v] = (__bf16)bp[v];
        } else {
            #pragma unroll
            for (int v = 0; v < 8; ++v) b[v] = (__bf16)0.0f;
        }
        acc = __builtin_amdgcn_mfma_f32_16x16x32_bf16(a, b, acc, 0, 0, 0);
    }
    #pragma unroll
    for (int r = 0; r < 4; ++r) {
        const int orow = mrow + gk * 4 + r;
        if (col < C_) out[(size_t)orow * C_ + col] = acc[r] * TINV;
    }
}

// ---------------- new_queue: first 1024 cols <- k^T, rest copy ----------------
__global__ __launch_bounds__(256) void queue_copy(const float* __restrict__ queue,
                                                  const float* __restrict__ k,
                                                  float* __restrict__ outq) {
    const size_t total = (size_t)D_ * K_ / 4;   // float4 count = 2,097,152
    for (size_t idx = (size_t)blockIdx.x * blockDim.x + threadIdx.x; idx < total;
         idx += (size_t)gridDim.x * blockDim.x) {
        const int d  = (int)(idx >> 14);          // / (K_/4)
        const int jj = (int)(idx & 16383) << 2;   // column
        float4 v;
        if (jj >= B_) {
            v = reinterpret_cast<const float4*>(queue)[idx];
        } else {
            v.x = k[(size_t)(jj + 0) * D_ + d];
            v.y = k[(size_t)(jj + 1) * D_ + d];
            v.z = k[(size_t)(jj + 2) * D_ + d];
            v.w = k[(size_t)(jj + 3) * D_ + d];
        }
        reinterpret_cast<float4*>(outq)[idx] = v;
    }
}

// ---------------- per-sample EMA weight: w_j = (1-m) * m^(n_c - occ_j) ----------------
__global__ __launch_bounds__(1024) void rank_kernel(const int* __restrict__ target,
                                                    float* __restrict__ w) {
    __shared__ int t[B_];
    const int j = threadIdx.x;
    t[j] = target[j];
    __syncthreads();
    const int mine = t[j];
    int total = 0, rank = 0;
    for (int i = 0; i < B_; ++i) {
        const bool h = (t[i] == mine);
        total += h ? 1 : 0;
        rank  += (h && i <= j) ? 1 : 0;
    }
    w[j] = 0.001f * powf(0.999f, (float)(total - rank));
}

// ---------------- new_prototypes: decay + weighted gather + l2norm ----------------
__global__ __launch_bounds__(128) void proto_update(const float* __restrict__ protos,
                                                    const float* __restrict__ q,
                                                    const int* __restrict__ target,
                                                    const float* __restrict__ w,
                                                    float* __restrict__ outp) {
    __shared__ int   t[B_];
    __shared__ float ww[B_];
    __shared__ float red[2];
    const int c = blockIdx.x, d = threadIdx.x;
    for (int i = d; i < B_; i += 128) { t[i] = target[i]; ww[i] = w[i]; }
    __syncthreads();

    float accv = 0.0f;
    int cnt = 0;
    for (int i = 0; i < B_; ++i) {
        if (t[i] == c) {   // wave-uniform branch (t[i] broadcast from LDS)
            ++cnt;
            accv = fmaf(ww[i], q[(size_t)i * D_ + d], accv);
        }
    }
    float val = fmaf(protos[(size_t)c * D_ + d], powf(0.999f, (float)cnt), accv);

    float ss = val * val;
    #pragma unroll
    for (int off = 32; off > 0; off >>= 1) ss += __shfl_xor(ss, off);
    if ((d & 63) == 0) red[d >> 6] = ss;
    __syncthreads();
    const float norm = sqrtf(red[0] + red[1]);
    outp[(size_t)c * D_ + d] = val / fmaxf(norm, 1e-12f);
}

extern "C" void kernel_launch(void* const* d_in, const int* in_sizes, int n_in,
                              void* d_out, int out_size, void* d_ws, size_t ws_size,
                              hipStream_t stream) {
    const float* q      = (const float*)d_in[0];
    const float* k      = (const float*)d_in[1];
    const float* queue  = (const float*)d_in[2];
    const float* protos = (const float*)d_in[3];
    const int*   target = (const int*)d_in[4];

    float* out    = (float*)d_out;
    float* logits = out;                                  // [1024][65537]
    float* lproto = out + (size_t)B_ * LROW;              // [1024][1000]
    float* outq   = lproto + (size_t)B_ * C_;             // [128][65536]
    float* outp   = outq + (size_t)D_ * K_;               // [1000][128]

    float* w = (float*)d_ws;                              // [1024] scratch

    lpos_kernel <<<B_ / 4, 256, 0, stream>>>(q, k, logits);
    rank_kernel <<<1, 1024, 0, stream>>>(target, w);
    gemm_neg    <<<dim3(K_ / 128, B_ / 128), 256, 0, stream>>>(q, queue, logits);
    gemm_proto  <<<dim3((C_ + 15) / 16, B_ / 64), 256, 0, stream>>>(q, protos, lproto);
    queue_copy  <<<2048, 256, 0, stream>>>(queue, k, outq);
    proto_update<<<C_, 128, 0, stream>>>(protos, q, target, w, outp);
}

// Round 2
// 172.925 us; speedup vs baseline: 1.4022x; 1.4022x over previous
//
#include <hip/hip_runtime.h>
#include <hip/hip_bf16.h>

typedef __bf16 bf16x8 __attribute__((ext_vector_type(8)));
typedef float  f32x4  __attribute__((ext_vector_type(4)));

// Sizes (fixed):
//   q [1024][128] f32, k [1024][128] f32, queue [128][65536] f32,
//   prototypes [1000][128] f32, target [1024] int32
// Outputs (concat f32): logits [1024][65537], logits_proto [1024][1000],
//   new_queue [128][65536], new_prototypes [1000][128]
// d_ws: Bt = bf16 queue^T [65536][128] (16.8 MB; ws observed ~1.2 GB).

#define B_   1024
#define D_   128
#define K_   65536
#define C_   1000
#define LROW 65537
#define TINV 10.0f

// ---- convert_T: read queue once; emit new_queue copy + bf16 transposed Bt ----
__global__ __launch_bounds__(256) void convert_T(const float* __restrict__ queue,
                                                 float* __restrict__ outq,
                                                 __bf16* __restrict__ Bt) {
    __shared__ __bf16 Lt[128][136];   // [c][d], row stride 272 B (16B-aligned)
    const int tid = threadIdx.x;
    const int c0  = blockIdx.x * 128;
    #pragma unroll
    for (int it = 0; it < 16; ++it) {
        const int idx = it * 256 + tid;          // float4 slot in 128x128 tile
        const int d   = idx >> 5;                // 32 float4 per d-row
        const int cq  = (idx & 31) * 4;
        const float4 v = *reinterpret_cast<const float4*>(queue + (size_t)d * K_ + c0 + cq);
        *reinterpret_cast<float4*>(outq + (size_t)d * K_ + c0 + cq) = v;
        Lt[cq + 0][d] = (__bf16)v.x;
        Lt[cq + 1][d] = (__bf16)v.y;
        Lt[cq + 2][d] = (__bf16)v.z;
        Lt[cq + 3][d] = (__bf16)v.w;
    }
    __syncthreads();
    #pragma unroll
    for (int it = 0; it < 8; ++it) {
        const int idx = it * 256 + tid;          // 16B chunk in 128x(128*2B) tile
        const int c   = idx >> 4;
        const int dc  = (idx & 15) * 8;
        const bf16x8 v = *reinterpret_cast<const bf16x8*>(&Lt[c][dc]);
        *reinterpret_cast<bf16x8*>(Bt + (size_t)(c0 + c) * D_ + dc) = v;
    }
}

// ---- l_pos: logits[:,0] = (q·k)/T ----
__global__ __launch_bounds__(256) void lpos_kernel(const float* __restrict__ q,
                                                   const float* __restrict__ k,
                                                   float* __restrict__ logits) {
    const int wid  = threadIdx.x >> 6;
    const int lane = threadIdx.x & 63;
    const int row  = blockIdx.x * 4 + wid;
    const float2 qv = reinterpret_cast<const float2*>(q + (size_t)row * D_)[lane];
    const float2 kv = reinterpret_cast<const float2*>(k + (size_t)row * D_)[lane];
    float p = qv.x * kv.x + qv.y * kv.y;
    #pragma unroll
    for (int off = 32; off > 0; off >>= 1) p += __shfl_xor(p, off);
    if (lane == 0) logits[(size_t)row * LROW] = p * TINV;
}

// ---- big GEMM: logits[:,1:] = (q @ queue)/T, B from bf16 Bt[K][D] ----
// grid (512, 8); XCD-bijective swizzle: xcd k owns col-tiles [k*64, k*64+64).
__global__ __launch_bounds__(256) void gemm_neg(const float* __restrict__ q,
                                                const __bf16* __restrict__ Bt,
                                                float* __restrict__ logits) {
    __shared__ __bf16 Alds[128][128];            // XOR-swizzled 16B blocks
    const int tid = threadIdx.x, wid = tid >> 6, lane = tid & 63;
    const int lin = blockIdx.y * 512 + blockIdx.x;       // 0..4095, x fastest
    const int xcd = lin & 7, j = lin >> 3;
    const int bcol = (xcd * 64 + (j >> 3)) * 128;
    const int brow = (j & 7) * 128;

    // stage A: q tile f32 -> bf16 LDS; 16B block (r, cb) stored at cb^(r&7)
    #pragma unroll
    for (int it = 0; it < 8; ++it) {
        const int idx = it * 256 + tid;          // 16B-block slot, 0..2047
        const int r   = idx >> 4;
        const int cb  = idx & 15;
        const float4 v0 = *reinterpret_cast<const float4*>(q + (size_t)(brow + r) * D_ + cb * 8);
        const float4 v1 = *reinterpret_cast<const float4*>(q + (size_t)(brow + r) * D_ + cb * 8 + 4);
        union { __bf16 h[8]; bf16x8 v; } t;
        t.h[0]=(__bf16)v0.x; t.h[1]=(__bf16)v0.y; t.h[2]=(__bf16)v0.z; t.h[3]=(__bf16)v0.w;
        t.h[4]=(__bf16)v1.x; t.h[5]=(__bf16)v1.y; t.h[6]=(__bf16)v1.z; t.h[7]=(__bf16)v1.w;
        *reinterpret_cast<bf16x8*>(&Alds[r][(cb ^ (r & 7)) * 8]) = t.v;
    }
    __syncthreads();

    const int bl = lane & 15, gk = lane >> 4;
    const int colbase = bcol + wid * 32;

    f32x4 acc[8][2] = {};
    #pragma unroll
    for (int s = 0; s < 4; ++s) {
        bf16x8 af[8];
        #pragma unroll
        for (int m = 0; m < 8; ++m) {
            const int r = m * 16 + bl;
            af[m] = *reinterpret_cast<const bf16x8*>(&Alds[r][(((s * 4 + gk) ^ (r & 7))) * 8]);
        }
        #pragma unroll
        for (int n = 0; n < 2; ++n) {
            const bf16x8 bfrag = *reinterpret_cast<const bf16x8*>(
                Bt + (size_t)(colbase + n * 16 + bl) * D_ + s * 32 + gk * 8);
            #pragma unroll
            for (int m = 0; m < 8; ++m)
                acc[m][n] = __builtin_amdgcn_mfma_f32_16x16x32_bf16(af[m], bfrag, acc[m][n], 0, 0, 0);
        }
    }

    // C/D: col = lane&15, row = (lane>>4)*4 + r
    #pragma unroll
    for (int m = 0; m < 8; ++m)
        #pragma unroll
        for (int n = 0; n < 2; ++n)
            #pragma unroll
            for (int r = 0; r < 4; ++r) {
                const int orow = brow + m * 16 + (gk << 2) + r;
                logits[(size_t)orow * LROW + 1 + colbase + n * 16 + bl] = acc[m][n][r] * TINV;
            }
}

// ---- proto GEMM: logits_proto = (q @ protos^T)/T ----
__global__ __launch_bounds__(256) void gemm_proto(const float* __restrict__ q,
                                                  const float* __restrict__ protos,
                                                  float* __restrict__ out) {
    const int wid  = threadIdx.x >> 6;
    const int lane = threadIdx.x & 63;
    const int mrow = (blockIdx.y * 4 + wid) * 16;
    const int ncol = blockIdx.x * 16;
    const int bl = lane & 15, gk = lane >> 4;
    const int col = ncol + bl;
    const bool valid = (col < C_);

    f32x4 acc = {};
    #pragma unroll
    for (int s = 0; s < 4; ++s) {
        const float* ap = q + (size_t)(mrow + bl) * D_ + s * 32 + gk * 8;
        bf16x8 a, b;
        #pragma unroll
        for (int v = 0; v < 8; ++v) a[v] = (__bf16)ap[v];
        if (valid) {
            const float* bp = protos + (size_t)col * D_ + s * 32 + gk * 8;
            #pragma unroll
            for (int v = 0; v < 8; ++v) b[v] = (__bf16)bp[v];
        } else {
            #pragma unroll
            for (int v = 0; v < 8; ++v) b[v] = (__bf16)0.0f;
        }
        acc = __builtin_amdgcn_mfma_f32_16x16x32_bf16(a, b, acc, 0, 0, 0);
    }
    #pragma unroll
    for (int r = 0; r < 4; ++r) {
        const int orow = mrow + gk * 4 + r;
        if (valid) out[(size_t)orow * C_ + col] = acc[r] * TINV;
    }
}

// ---- kT_patch: new_queue[d][c] = k[c][d] for c < 1024 ----
__global__ __launch_bounds__(256) void kT_patch(const float* __restrict__ k,
                                                float* __restrict__ outq) {
    __shared__ float Lf[128][129];
    const int tid = threadIdx.x;
    const int c0  = blockIdx.x * 128;
    #pragma unroll
    for (int it = 0; it < 16; ++it) {
        const int idx = it * 256 + tid;
        const int c   = idx >> 5;
        const int dq  = (idx & 31) * 4;
        const float4 v = *reinterpret_cast<const float4*>(k + (size_t)(c0 + c) * D_ + dq);
        Lf[dq + 0][c] = v.x; Lf[dq + 1][c] = v.y; Lf[dq + 2][c] = v.z; Lf[dq + 3][c] = v.w;
    }
    __syncthreads();
    #pragma unroll
    for (int it = 0; it < 16; ++it) {
        const int idx = it * 256 + tid;
        const int d   = idx >> 5;
        const int cq  = (idx & 31) * 4;
        float4 v;
        v.x = Lf[d][cq + 0]; v.y = Lf[d][cq + 1]; v.z = Lf[d][cq + 2]; v.w = Lf[d][cq + 3];
        *reinterpret_cast<float4*>(outq + (size_t)d * K_ + c0 + cq) = v;
    }
}

// ---- new_prototypes: single-pass EMA (w folded: m^cnt*(p + 0.001*sum m^-occ q)) ----
__global__ __launch_bounds__(128) void proto_update(const float* __restrict__ protos,
                                                    const float* __restrict__ q,
                                                    const int* __restrict__ target,
                                                    float* __restrict__ outp) {
    __shared__ int   t[B_];
    __shared__ float red[2];
    const int c = blockIdx.x, d = threadIdx.x;
    for (int i = d; i < B_; i += 128) t[i] = target[i];
    __syncthreads();

    float acc = 0.0f, wgt = 1.0f;
    int cnt = 0;
    for (int i = 0; i < B_; ++i) {
        if (t[i] == c) {                 // wave-uniform (LDS broadcast)
            ++cnt;
            wgt *= 1.0010010010010010f;  // 1/0.999 -> m^(-occ_i)
            acc = fmaf(wgt, q[(size_t)i * D_ + d], acc);
        }
    }
    const float val = powf(0.999f, (float)cnt) *
                      fmaf(0.001f, acc, protos[(size_t)c * D_ + d]);

    float ss = val * val;
    #pragma unroll
    for (int off = 32; off > 0; off >>= 1) ss += __shfl_xor(ss, off);
    if ((d & 63) == 0) red[d >> 6] = ss;
    __syncthreads();
    const float norm = sqrtf(red[0] + red[1]);
    outp[(size_t)c * D_ + d] = val / fmaxf(norm, 1e-12f);
}

extern "C" void kernel_launch(void* const* d_in, const int* in_sizes, int n_in,
                              void* d_out, int out_size, void* d_ws, size_t ws_size,
                              hipStream_t stream) {
    const float* q      = (const float*)d_in[0];
    const float* k      = (const float*)d_in[1];
    const float* queue  = (const float*)d_in[2];
    const float* protos = (const float*)d_in[3];
    const int*   target = (const int*)d_in[4];

    float* out    = (float*)d_out;
    float* logits = out;                                  // [1024][65537]
    float* lproto = out + (size_t)B_ * LROW;              // [1024][1000]
    float* outq   = lproto + (size_t)B_ * C_;             // [128][65536]
    float* outp   = outq + (size_t)D_ * K_;               // [1000][128]

    __bf16* Bt = (__bf16*)d_ws;                           // [65536][128] bf16

    convert_T   <<<K_ / 128, 256, 0, stream>>>(queue, outq, Bt);
    lpos_kernel <<<B_ / 4, 256, 0, stream>>>(q, k, logits);
    gemm_neg    <<<dim3(512, 8), 256, 0, stream>>>(q, Bt, logits);
    gemm_proto  <<<dim3((C_ + 15) / 16, B_ / 64), 256, 0, stream>>>(q, protos, lproto);
    kT_patch    <<<B_ / 128, 256, 0, stream>>>(k, outq);
    proto_update<<<C_, 128, 0, stream>>>(protos, q, target, outp);
}